// Round 7
// baseline (113.438 us; speedup 1.0000x reference)
//
#include <hip/hip_runtime.h>

// FuzzySystemLayer, single fused kernel. B=262144, C=256, D=64, O=8 (fp32).
// GEMM1 in fp16 (32x32x16_f16): acc[c_row, b_col] = log2-domain exponent
//   e = (2*x.c)*k - k*x^2 - k*c^2,  k = log2(e)/(2 w^2)
//   5 K-blocks: 4x [A=fp16(2k*c) x B=fp16(x)] + 1 affine block (hi/lo fp16
//   splits of k, x^2, k*c^2; pair error ~2^-22).
// GEMM2 in bf16 (memb spans 2^-40..2^-200: fp16 would flush to zero).
//   out2[o,b] = W'^T @ memb, W' row 8 = ones -> normalizer.
// Cluster rows permuted by swap23 so exp2(acc) registers ARE GEMM2 B-fragments.
// R2 lesson: no local array indexed by runtime var (scratch demotion).
// R4 lesson: fragment loads from L2 were the latency wall -> LDS staging.
// R6 lesson: B-operand x slice is h-dependent: lane holds k = kd*16 + h*8 + j.
//   Hoisted loads MUST use xp[4*kd + 2*h + i] — flat xp[q] broke correctness.

#define NB 262144
#define NC 256
#define ND 64
#define NO 8

typedef __attribute__((ext_vector_type(8))) short short8;
typedef __attribute__((ext_vector_type(8))) _Float16 half8;
typedef __attribute__((ext_vector_type(16))) float floatx16;

// LDS layout in shorts:
//   A (fp16):  ((t*5 + idx)*64 + lane)*8 + j   idx 0..3 = 2k*c, idx 4 = affine
//   W (bf16):  20480 + (k2*64 + lane)*8 + j    k2 = 0..15
#define WOFF 20480
#define WS_SHORTS 28672  // 56 KB

__device__ inline unsigned short f2bf(float f) {
    unsigned u = __builtin_bit_cast(unsigned, f);
    u = u + 0x7FFFu + ((u >> 16) & 1u);
    return (unsigned short)(u >> 16);
}

__global__ __launch_bounds__(512, 4) void fuzzy_main(
    const float* __restrict__ x,
    const float* __restrict__ centers,
    const float* __restrict__ widths,
    const float* __restrict__ W,
    float* __restrict__ out) {
    __shared__ short lds_s[WS_SHORTS];

    const int tid = threadIdx.x;
    const int wave = tid >> 6;
    const int lane = tid & 63;
    const int col = lane & 31;
    const int h = lane >> 5;
    const int bbase = (blockIdx.x * 8 + wave) * 64;  // 64 b-columns per wave

    // ---- issue raw x loads first (long-latency; convert after prep) ----
    // Lane's B-fragment slice for K-block kd is dims [kd*16 + h*8, +8):
    // float4 indices 4*kd + 2*h and 4*kd + 2*h + 1.   (R6 bug: was xp[q]!)
    float4 xr[2][8];
#pragma unroll
    for (int u = 0; u < 2; ++u) {
        const float4* xp = (const float4*)(x + (size_t)(bbase + u * 32 + col) * ND);
#pragma unroll
        for (int kd = 0; kd < 4; ++kd) {
            xr[u][2 * kd + 0] = xp[4 * kd + 2 * h + 0];
            xr[u][2 * kd + 1] = xp[4 * kd + 2 * h + 1];
        }
    }

    // ---- fused prep: wave t builds tile t's fragments into LDS ----
    {
        const int t = wave;
        // cluster at GEMM1 row `col` of tile t: swap bits 2<->3 (self-inverse)
        const int c = 32 * t + ((col & 19) | ((col & 4) << 1) | ((col & 8) >> 1));
        const float* cr = centers + c * ND;
        float vv[4][8];
        float part = 0.0f;
#pragma unroll
        for (int kd = 0; kd < 4; ++kd) {
            const float4* p = (const float4*)(cr + kd * 16 + h * 8);
            float4 a0 = p[0], a1 = p[1];
            vv[kd][0] = a0.x; vv[kd][1] = a0.y; vv[kd][2] = a0.z; vv[kd][3] = a0.w;
            vv[kd][4] = a1.x; vv[kd][5] = a1.y; vv[kd][6] = a1.z; vv[kd][7] = a1.w;
#pragma unroll
            for (int j = 0; j < 8; ++j) part = fmaf(vv[kd][j], vv[kd][j], part);
        }
        float csq = part + __shfl_xor(part, 32, 64);
        float w = widths[c];
        float kk = 1.4426950408889634f / (2.0f * w * w);  // log2(e)/(2w^2)

#pragma unroll
        for (int kd = 0; kd < 4; ++kd) {
            half8 ah;
#pragma unroll
            for (int j = 0; j < 8; ++j) ah[j] = (_Float16)(2.0f * kk * vv[kd][j]);
            *(half8*)&lds_s[((t * 5 + kd) * 64 + lane) * 8] = ah;
        }
        // affine block (idx 4), nonzero only on h==0:
        // A = [-k_h, -k_h, -k_l, -(kc^2)_h, -(kc^2)_l, 0,0,0]
        // pairs B = [x2_h, x2_l, x2_h, 1, 1, 0,0,0]
        half8 av;
#pragma unroll
        for (int j = 0; j < 8; ++j) av[j] = (_Float16)0.0f;
        if (h == 0) {
            float kh = (float)(_Float16)kk;
            float kl = kk - kh;
            float Bc = csq * kk;
            float Bh = (float)(_Float16)Bc;
            float Bl = Bc - Bh;
            av[0] = (_Float16)(-kh);
            av[1] = (_Float16)(-kh);
            av[2] = (_Float16)(-kl);
            av[3] = (_Float16)(-Bh);
            av[4] = (_Float16)(-Bl);
        }
        *(half8*)&lds_s[((t * 5 + 4) * 64 + lane) * 8] = av;

        // W' fragments (bf16): A[m=o][k=c]; o=col; row 8 = ones (normalizer)
#pragma unroll
        for (int q = 0; q < 2; ++q) {
            int k2 = 2 * t + q;
            short8 wf;
#pragma unroll
            for (int j = 0; j < 8; ++j) {
                int c2 = k2 * 16 + h * 8 + j;  // natural order (perm self-inverts)
                float val = (col < NO) ? W[c2 * NO + col] : (col == 8 ? 1.0f : 0.0f);
                wf[j] = (short)f2bf(val);
            }
            *(short8*)&lds_s[WOFF + (k2 * 64 + lane) * 8] = wf;
        }
    }

    // ---- convert x rows: fp16 fragments, xsq, affine pair f12 ----
    half8 xh[2][4];
    half8 f12[2];
#pragma unroll
    for (int u = 0; u < 2; ++u) {
        float part = 0.0f;
#pragma unroll
        for (int kd = 0; kd < 4; ++kd) {
            float4 v0 = xr[u][2 * kd], v1 = xr[u][2 * kd + 1];
            float v[8] = {v0.x, v0.y, v0.z, v0.w, v1.x, v1.y, v1.z, v1.w};
            half8 hh;
#pragma unroll
            for (int j = 0; j < 8; ++j) {
                part = fmaf(v[j], v[j], part);
                hh[j] = (_Float16)v[j];
            }
            xh[u][kd] = hh;
        }
        float xsq = part + __shfl_xor(part, 32, 64);
        float sh = (float)(_Float16)xsq;
        float sl = xsq - sh;
        half8 f;
#pragma unroll
        for (int j = 0; j < 8; ++j) f[j] = (_Float16)0.0f;
        if (h == 0) {
            f[0] = (_Float16)sh;
            f[1] = (_Float16)sl;
            f[2] = (_Float16)sh;
            f[3] = (_Float16)1.0f;
            f[4] = (_Float16)1.0f;
        }
        f12[u] = f;
    }

    __syncthreads();

    floatx16 acc2[2];
#pragma unroll
    for (int u = 0; u < 2; ++u)
#pragma unroll
        for (int i = 0; i < 16; ++i) acc2[u][i] = 0.0f;

#pragma unroll 2
    for (int t = 0; t < 8; ++t) {
        const half8 A0 = *(const half8*)&lds_s[((t * 5 + 0) * 64 + lane) * 8];
        const half8 A1 = *(const half8*)&lds_s[((t * 5 + 1) * 64 + lane) * 8];
        const half8 A2 = *(const half8*)&lds_s[((t * 5 + 2) * 64 + lane) * 8];
        const half8 A3 = *(const half8*)&lds_s[((t * 5 + 3) * 64 + lane) * 8];
        const half8 C12 = *(const half8*)&lds_s[((t * 5 + 4) * 64 + lane) * 8];
        const short8 w0 = *(const short8*)&lds_s[WOFF + ((2 * t + 0) * 64 + lane) * 8];
        const short8 w1 = *(const short8*)&lds_s[WOFF + ((2 * t + 1) * 64 + lane) * 8];

#pragma unroll
        for (int u = 0; u < 2; ++u) {
            floatx16 acc;
#pragma unroll
            for (int i = 0; i < 16; ++i) acc[i] = 0.0f;
            acc = __builtin_amdgcn_mfma_f32_32x32x16_f16(A0, xh[u][0], acc, 0, 0, 0);
            acc = __builtin_amdgcn_mfma_f32_32x32x16_f16(A1, xh[u][1], acc, 0, 0, 0);
            acc = __builtin_amdgcn_mfma_f32_32x32x16_f16(A2, xh[u][2], acc, 0, 0, 0);
            acc = __builtin_amdgcn_mfma_f32_32x32x16_f16(A3, xh[u][3], acc, 0, 0, 0);
            acc = __builtin_amdgcn_mfma_f32_32x32x16_f16(C12, f12[u], acc, 0, 0, 0);

            // exp2 -> bf16 (RTZ) two-at-a-time via v_perm
            unsigned p0 = __builtin_bit_cast(unsigned, __builtin_amdgcn_exp2f(acc[0]));
            unsigned p1 = __builtin_bit_cast(unsigned, __builtin_amdgcn_exp2f(acc[1]));
            unsigned p2 = __builtin_bit_cast(unsigned, __builtin_amdgcn_exp2f(acc[2]));
            unsigned p3 = __builtin_bit_cast(unsigned, __builtin_amdgcn_exp2f(acc[3]));
            unsigned p4 = __builtin_bit_cast(unsigned, __builtin_amdgcn_exp2f(acc[4]));
            unsigned p5 = __builtin_bit_cast(unsigned, __builtin_amdgcn_exp2f(acc[5]));
            unsigned p6 = __builtin_bit_cast(unsigned, __builtin_amdgcn_exp2f(acc[6]));
            unsigned p7 = __builtin_bit_cast(unsigned, __builtin_amdgcn_exp2f(acc[7]));
            unsigned p8 = __builtin_bit_cast(unsigned, __builtin_amdgcn_exp2f(acc[8]));
            unsigned p9 = __builtin_bit_cast(unsigned, __builtin_amdgcn_exp2f(acc[9]));
            unsigned pa = __builtin_bit_cast(unsigned, __builtin_amdgcn_exp2f(acc[10]));
            unsigned pb = __builtin_bit_cast(unsigned, __builtin_amdgcn_exp2f(acc[11]));
            unsigned pc = __builtin_bit_cast(unsigned, __builtin_amdgcn_exp2f(acc[12]));
            unsigned pd = __builtin_bit_cast(unsigned, __builtin_amdgcn_exp2f(acc[13]));
            unsigned pe = __builtin_bit_cast(unsigned, __builtin_amdgcn_exp2f(acc[14]));
            unsigned pf = __builtin_bit_cast(unsigned, __builtin_amdgcn_exp2f(acc[15]));
            uint4 q0, q1;
            q0.x = __builtin_amdgcn_perm(p1, p0, 0x07060302u);
            q0.y = __builtin_amdgcn_perm(p3, p2, 0x07060302u);
            q0.z = __builtin_amdgcn_perm(p5, p4, 0x07060302u);
            q0.w = __builtin_amdgcn_perm(p7, p6, 0x07060302u);
            q1.x = __builtin_amdgcn_perm(p9, p8, 0x07060302u);
            q1.y = __builtin_amdgcn_perm(pb, pa, 0x07060302u);
            q1.z = __builtin_amdgcn_perm(pd, pc, 0x07060302u);
            q1.w = __builtin_amdgcn_perm(pf, pe, 0x07060302u);
            short8 pf0 = __builtin_bit_cast(short8, q0);
            short8 pf1 = __builtin_bit_cast(short8, q1);

            acc2[u] = __builtin_amdgcn_mfma_f32_32x32x16_bf16(w0, pf0, acc2[u], 0, 0, 0);
            acc2[u] = __builtin_amdgcn_mfma_f32_32x32x16_bf16(w1, pf1, acc2[u], 0, 0, 0);
        }
    }

    // ---- epilogue per b-tile ----
#pragma unroll
    for (int u = 0; u < 2; ++u) {
        float S = acc2[u][4];  // row 8 (normalizer) lives at h==0, reg 4
        float Sp = __shfl_xor(S, 32, 64);
        if (h) S = Sp;
        float inv = 1.0f / S;
        float4 r;
        r.x = acc2[u][0] * inv;
        r.y = acc2[u][1] * inv;
        r.z = acc2[u][2] * inv;
        r.w = acc2[u][3] * inv;
        // h=0 lanes hold o=0..3, h=1 lanes hold o=4..7 of the same b
        ((float4*)(out + (size_t)(bbase + u * 32 + col) * NO))[h] = r;
    }
}

extern "C" void kernel_launch(void* const* d_in, const int* in_sizes, int n_in,
                              void* d_out, int out_size, void* d_ws, size_t ws_size,
                              hipStream_t stream) {
    const float* x       = (const float*)d_in[0];  // [B, D]
    const float* centers = (const float*)d_in[1];  // [C, D]
    const float* widths  = (const float*)d_in[2];  // [C]
    const float* W       = (const float*)d_in[3];  // [C, O]
    float* out = (float*)d_out;
    (void)d_ws; (void)ws_size;

    // 512 blocks x 512 threads; each wave: 64 b-columns + builds 1/8 of LDS frags
    fuzzy_main<<<NB / 512, 512, 0, stream>>>(x, centers, widths, W, out);
}